// Round 3
// baseline (268.686 us; speedup 1.0000x reference)
//
#include <hip/hip_runtime.h>
#include <cstdint>
#include <cstddef>

#define SEQ 4096
#define DH 2048
#define DOUT 1024

typedef float f32x4 __attribute__((ext_vector_type(4)));
typedef __bf16 bf16x8 __attribute__((ext_vector_type(8)));

// ---- helpers --------------------------------------------------------------

__device__ __forceinline__ unsigned short f2bf(float f) {
  // round-to-nearest-even fp32 -> bf16 (inputs are finite; no NaN handling)
  unsigned int u = __float_as_uint(f);
  unsigned int r = (u + 0x7FFFu + ((u >> 16) & 1u)) >> 16;
  return (unsigned short)r;
}

__device__ __forceinline__ void g2l16(const unsigned short* g, unsigned short* l) {
  // async global -> LDS, 16 bytes per lane. LDS side is wave-uniform base + lane*16.
  __builtin_amdgcn_global_load_lds((__attribute__((address_space(1))) void*)(void*)g,
                                   (__attribute__((address_space(3))) void*)l, 16, 0, 0);
}

// ---- kernel 1: per-row mean / rstd of gate half ---------------------------

__global__ __launch_bounds__(256) void ln_stats(const float* __restrict__ x,
                                                float* __restrict__ mv,
                                                float* __restrict__ rv) {
  int row = blockIdx.x;
  const float4* g4 = (const float4*)(x + (size_t)row * (2 * DH) + DH);
  float4 a = g4[threadIdx.x];
  float4 b = g4[threadIdx.x + 256];
  float s  = a.x + a.y + a.z + a.w + b.x + b.y + b.z + b.w;
  float s2 = a.x * a.x + a.y * a.y + a.z * a.z + a.w * a.w +
             b.x * b.x + b.y * b.y + b.z * b.z + b.w * b.w;
#pragma unroll
  for (int o = 32; o > 0; o >>= 1) {
    s  += __shfl_down(s, o);
    s2 += __shfl_down(s2, o);
  }
  __shared__ float red[8];
  int wave = threadIdx.x >> 6;
  if ((threadIdx.x & 63) == 0) { red[wave] = s; red[wave + 4] = s2; }
  __syncthreads();
  if (threadIdx.x == 0) {
    float S  = red[0] + red[1] + red[2] + red[3];
    float S2 = red[4] + red[5] + red[6] + red[7];
    float mean = S * (1.0f / DH);
    float var  = S2 * (1.0f / DH) - mean * mean;  // ddof=0, matches jnp.var
    mv[row] = mean;
    rv[row] = rsqrtf(var + 1e-5f);
  }
}

// ---- kernel 2: normalize + scale + transpose + cast -> gateT[d][n] bf16 ---

__global__ __launch_bounds__(256) void norm_tr(const float* __restrict__ x,
                                               const float* __restrict__ mv,
                                               const float* __restrict__ rv,
                                               const float* __restrict__ lns,
                                               unsigned short* __restrict__ gateT) {
  __shared__ float tile[64][65];  // +1 pad: conflict-free transposed reads
  int d0 = blockIdx.x * 64;  // d-tile (0..2047)
  int n0 = blockIdx.y * 64;  // n-tile (0..4095)
#pragma unroll
  for (int i = 0; i < 16; i++) {
    int idx = threadIdx.x + i * 256;
    int r = idx >> 6, c = idx & 63;  // r = n offset, c = d offset (coalesced in c)
    float v = x[(size_t)(n0 + r) * (2 * DH) + DH + d0 + c];
    tile[r][c] = (v - mv[n0 + r]) * rv[n0 + r];
  }
  __syncthreads();
#pragma unroll
  for (int i = 0; i < 16; i++) {
    int idx = threadIdx.x + i * 256;
    int dr = idx >> 6, nc = idx & 63;  // coalesced in nc
    float v = tile[nc][dr] * lns[d0 + dr];
    gateT[(size_t)(d0 + dr) * SEQ + n0 + nc] = f2bf(v);
  }
}

// ---- kernel 3: tril-masked cast w fp32 -> bf16 ----------------------------

__global__ __launch_bounds__(256) void cast_w_tril(const float* __restrict__ w,
                                                   unsigned short* __restrict__ wb) {
  size_t e = ((size_t)blockIdx.x * 256 + threadIdx.x) * 8;
  int m = (int)(e >> 12);    // row (4096 = 2^12 cols)
  int k = (int)(e & 4095);   // col
  uint4 o;
  if (k + 7 <= m) {  // fully inside lower triangle
    const float4* s = (const float4*)(w + e);
    float4 a = s[0], b = s[1];
    o.x = (unsigned)f2bf(a.x) | ((unsigned)f2bf(a.y) << 16);
    o.y = (unsigned)f2bf(a.z) | ((unsigned)f2bf(a.w) << 16);
    o.z = (unsigned)f2bf(b.x) | ((unsigned)f2bf(b.y) << 16);
    o.w = (unsigned)f2bf(b.z) | ((unsigned)f2bf(b.w) << 16);
  } else if (k > m) {  // fully above diagonal: no read needed
    o.x = o.y = o.z = o.w = 0u;
  } else {  // straddles the diagonal
    unsigned short t[8];
#pragma unroll
    for (int j = 0; j < 8; j++) t[j] = (k + j <= m) ? f2bf(w[e + j]) : (unsigned short)0;
    o.x = (unsigned)t[0] | ((unsigned)t[1] << 16);
    o.y = (unsigned)t[2] | ((unsigned)t[3] << 16);
    o.z = (unsigned)t[4] | ((unsigned)t[5] << 16);
    o.w = (unsigned)t[6] | ((unsigned)t[7] << 16);
  }
  *(uint4*)(wb + e) = o;
}

// ---- kernel 4: transpose + cast proj_w -> projT[j][d] bf16 ----------------

__global__ __launch_bounds__(256) void proj_tr(const float* __restrict__ pw,
                                               unsigned short* __restrict__ pT) {
  __shared__ float tile[64][65];
  int j0 = blockIdx.x * 64;  // out-col tile (0..1023)
  int d0 = blockIdx.y * 64;  // d tile (0..2047)
#pragma unroll
  for (int i = 0; i < 16; i++) {
    int idx = threadIdx.x + i * 256;
    int r = idx >> 6, c = idx & 63;  // r = d offset, c = j offset
    tile[r][c] = pw[(size_t)(d0 + r) * DOUT + j0 + c];
  }
  __syncthreads();
#pragma unroll
  for (int i = 0; i < 16; i++) {
    int idx = threadIdx.x + i * 256;
    int jr = idx >> 6, dc = idx & 63;
    pT[(size_t)(j0 + jr) * DH + d0 + dc] = f2bf(tile[dc][jr]);
  }
}

// ---- MFMA GEMM, 128x64 tile, BK=64, DOUBLE-BUFFERED 2-phase ---------------
// C = A(MxK) * BT(NxK)^T, bf16 in / fp32 acc. 256 threads = 4 waves (2x2);
// each wave owns a 64x32 subtile = 4x2 16x16 acc frags, 16 MFMA + 12
// ds_read_b128 per wave per BK=64 step.
//
// WHY 128x64 (round-2 post-mortem): this structure is LDS-traffic bound —
// total LDS bytes = #block-K-steps x (2x tile re-read + stage write).
// BM=128/BN=64 halves GEMM1's block-K-steps vs 64x128 (16896 vs 33280 ->
// ~18us LDS-pipe model) while keeping 512 blocks = 2/CU resident
// (LDS 48KB, ~130 VGPR). Round-1 showed 2/CU with drain-per-step stalls;
// hence:
//
// 2-PHASE DBUF (T3 minimum recipe): issue next tile's global_load_lds into
// buf^1 BEFORE computing buf, one __syncthreads (vmcnt+lgkm drain) per
// K-step. The drain then waits on loads that aged a full compute phase
// (~600cy) -> L2/HBM latency off the critical path even at 2 blocks/CU.
//
// PAIR (GEMM1 causal): gridDim.y=16; block p does row-blocks {p, 31-p}
// sequentially, each to its diagonal -> exactly 66 k-steps per block,
// perfectly uniform (round-2 lesson: per-CU WORK balance is not enough,
// block LIFETIMES must be uniform or residency decays to ~2 avg).
// A is pre-masked to tril so diagonal tiles are exact.
// EPI==1: P[m][n] = bf16( xfull[m][n] * (acc + rbias[m]) )
// EPI==2: out[m][n] = acc + cbias[n]
//
// LDS: 128 B rows (BK=64 bf16) = exactly 32 banks; XOR-8 chunk swizzle
// (data chunk c of row R at physical chunk c^(R&7)) -> conflict-free frag
// reads (0 SQ_LDS_BANK_CONFLICT measured rounds 0-2).

template <int BM, int BN, int EPI, bool PAIR>
__global__ __launch_bounds__(256) void gemm_db(const unsigned short* __restrict__ A,
                                               const unsigned short* __restrict__ BT,
                                               const float* __restrict__ xfull,
                                               const float* __restrict__ rbias,
                                               unsigned short* __restrict__ Pout,
                                               const float* __restrict__ cbias,
                                               float* __restrict__ out,
                                               int N, int K) {
  constexpr int BK = 64;
  constexpr int MI = BM / 32;                    // acc frags per wave, rows
  constexpr int NJ = BN / 32;                    // acc frags per wave, cols
  constexpr int ARPT = (BM * BK) / (256 * 8);    // A 16B-chunks per thread
  constexpr int BRPT = (BN * BK) / (256 * 8);    // B 16B-chunks per thread
  constexpr int ASZ = BM * BK, BSZ = BN * BK;

  __shared__ unsigned short sA[2 * ASZ];
  __shared__ unsigned short sB[2 * BSZ];

  const int tid = threadIdx.x;
  const int lane = tid & 63, wave = tid >> 6;
  const int quad = lane >> 4, l16 = lane & 15;
  const int wm = wave >> 1, wn = wave & 1;
  const int bn0 = blockIdx.x * BN;

  const int nPass = PAIR ? 2 : 1;
  for (int pass = 0; pass < nPass; pass++) {
    const int by = PAIR ? (pass == 0 ? (int)blockIdx.y
                                     : (2 * (int)gridDim.y - 1 - (int)blockIdx.y))
                        : (int)blockIdx.y;
    const int bm0 = by * BM;
    const int nt = (PAIR ? (bm0 + BM) : K) / BK;  // k-steps this pass (>=2)

    // staging source pointers (row/chunk swizzled), advance by BK per step
    const unsigned short* aP[ARPT];
    const unsigned short* bP[BRPT];
#pragma unroll
    for (int r = 0; r < ARPT; r++) {
      int idx = r * 256 + tid;
      int row = idx >> 3;
      int col = ((idx & 7) ^ (row & 7)) * 8;
      aP[r] = A + (size_t)(bm0 + row) * K + col;
    }
#pragma unroll
    for (int r = 0; r < BRPT; r++) {
      int idx = r * 256 + tid;
      int row = idx >> 3;
      int col = ((idx & 7) ^ (row & 7)) * 8;
      bP[r] = BT + (size_t)(bn0 + row) * K + col;
    }

    f32x4 acc[MI][NJ] = {};

    auto stage = [&](int buf) {
#pragma unroll
      for (int r = 0; r < ARPT; r++) {
        g2l16(aP[r], &sA[buf * ASZ + (r * 256 + tid) * 8]);
        aP[r] += BK;
      }
#pragma unroll
      for (int r = 0; r < BRPT; r++) {
        g2l16(bP[r], &sB[buf * BSZ + (r * 256 + tid) * 8]);
        bP[r] += BK;
      }
    };

    auto compute = [&](int buf) {
      const unsigned short* bA = &sA[buf * ASZ];
      const unsigned short* bB = &sB[buf * BSZ];
      bf16x8 af[2][MI], bfr[2][NJ];
#pragma unroll
      for (int h = 0; h < 2; h++) {
#pragma unroll
        for (int i = 0; i < MI; i++) {
          int R = wm * (BM / 2) + i * 16 + l16;
          af[h][i] = *(const bf16x8*)&bA[R * BK + (((h * 4 + quad) ^ (R & 7)) * 8)];
        }
#pragma unroll
        for (int j = 0; j < NJ; j++) {
          int R = wn * (BN / 2) + j * 16 + l16;
          bfr[h][j] = *(const bf16x8*)&bB[R * BK + (((h * 4 + quad) ^ (R & 7)) * 8)];
        }
      }
#pragma unroll
      for (int h = 0; h < 2; h++)
#pragma unroll
        for (int i = 0; i < MI; i++)
#pragma unroll
          for (int j = 0; j < NJ; j++)
            acc[i][j] = __builtin_amdgcn_mfma_f32_16x16x32_bf16(af[h][i], bfr[h][j], acc[i][j], 0, 0, 0);
    };

    if (pass) __syncthreads();  // prior pass's LDS reads must finish before restage
    stage(0);
    __syncthreads();            // drain prologue loads

    int cur = 0;
    for (int t = 0; t < nt - 1; t++) {
      stage(cur ^ 1);           // issue next tile FIRST (ages during compute)
      compute(cur);
      __syncthreads();          // drains vmcnt (stage) + lgkm (ds_reads)
      cur ^= 1;
    }
    compute(cur);               // last tile, nothing in flight

    // epilogue — C/D layout: col = lane&15, row = quad*4 + reg (m89-verified)
#pragma unroll
    for (int i = 0; i < MI; i++) {
#pragma unroll
      for (int j = 0; j < NJ; j++) {
        int col = bn0 + wn * (BN / 2) + j * 16 + l16;
#pragma unroll
        for (int r = 0; r < 4; r++) {
          int row = bm0 + wm * (BM / 2) + i * 16 + quad * 4 + r;
          float v = acc[i][j][r];
          if (EPI == 1) {
            float g = v + rbias[row];
            float pv = xfull[(size_t)row * (2 * DH) + col] * g;
            Pout[(size_t)row * N + col] = f2bf(pv);
          } else {
            out[(size_t)row * N + col] = v + cbias[col];
          }
        }
      }
    }
  }
}

// ---- launch ---------------------------------------------------------------

extern "C" void kernel_launch(void* const* d_in, const int* in_sizes, int n_in,
                              void* d_out, int out_size, void* d_ws, size_t ws_size,
                              hipStream_t stream) {
  (void)in_sizes; (void)n_in; (void)out_size; (void)ws_size;
  const float* x   = (const float*)d_in[0];
  const float* lns = (const float*)d_in[1];
  const float* w   = (const float*)d_in[2];
  const float* sb  = (const float*)d_in[3];
  const float* pw  = (const float*)d_in[4];
  const float* pb  = (const float*)d_in[5];
  float* out = (float*)d_out;

  char* p = (char*)d_ws;
  unsigned short* gateT = (unsigned short*)p; p += (size_t)DH * SEQ * 2;    // 16 MB
  unsigned short* wb    = (unsigned short*)p; p += (size_t)SEQ * SEQ * 2;   // 32 MB
  unsigned short* projT = (unsigned short*)p; p += (size_t)DOUT * DH * 2;   //  4 MB
  unsigned short* Pbuf  = (unsigned short*)p; p += (size_t)SEQ * DH * 2;    // 16 MB
  float* mv = (float*)p; p += (size_t)SEQ * 4;
  float* rv = (float*)p; p += (size_t)SEQ * 4;

  ln_stats<<<SEQ, 256, 0, stream>>>(x, mv, rv);
  norm_tr<<<dim3(DH / 64, SEQ / 64), 256, 0, stream>>>(x, mv, rv, lns, gateT);
  cast_w_tril<<<(int)(((size_t)SEQ * SEQ / 8) / 256), 256, 0, stream>>>(w, wb);
  proj_tr<<<dim3(DOUT / 64, DH / 64), 256, 0, stream>>>(pw, projT);

  // GEMM1: gate2 = tril(w) @ gate  (M=4096, N=2048, K=4096, causal)
  // 128x64 tiles, PAIR {p,31-p} -> 66 uniform k-steps/block,
  // grid (32,16)=512 blocks (2/CU), double-buffered 2-phase.
  gemm_db<128, 64, 1, true><<<dim3(DH / 64, SEQ / 256), 256, 0, stream>>>(
      wb, gateT, x, sb, Pbuf, nullptr, nullptr, DH, SEQ);
  // GEMM2: out = P @ proj_w + proj_b  (M=4096, N=1024, K=2048)
  // 128x64 tiles, grid (16,32)=512 blocks (2/CU), 32 uniform k-steps.
  gemm_db<128, 64, 2, false><<<dim3(DOUT / 64, SEQ / 128), 256, 0, stream>>>(
      Pbuf, projT, nullptr, nullptr, nullptr, pb, out, DOUT, DH);
}

// Round 4
// 253.866 us; speedup vs baseline: 1.0584x; 1.0584x over previous
//
#include <hip/hip_runtime.h>
#include <cstdint>
#include <cstddef>

#define SEQ 4096
#define DH 2048
#define DOUT 1024

typedef float f32x4 __attribute__((ext_vector_type(4)));
typedef __bf16 bf16x8 __attribute__((ext_vector_type(8)));

// ---- helpers --------------------------------------------------------------

__device__ __forceinline__ unsigned short f2bf(float f) {
  // round-to-nearest-even fp32 -> bf16 (inputs are finite; no NaN handling)
  unsigned int u = __float_as_uint(f);
  unsigned int r = (u + 0x7FFFu + ((u >> 16) & 1u)) >> 16;
  return (unsigned short)r;
}

__device__ __forceinline__ void g2l16(const unsigned short* g, unsigned short* l) {
  // async global -> LDS, 16 bytes per lane. LDS side is wave-uniform base + lane*16.
  __builtin_amdgcn_global_load_lds((__attribute__((address_space(1))) void*)(void*)g,
                                   (__attribute__((address_space(3))) void*)l, 16, 0, 0);
}

// ---- kernel 1: per-row mean / rstd of gate half ---------------------------

__global__ __launch_bounds__(256) void ln_stats(const float* __restrict__ x,
                                                float* __restrict__ mv,
                                                float* __restrict__ rv) {
  int row = blockIdx.x;
  const float4* g4 = (const float4*)(x + (size_t)row * (2 * DH) + DH);
  float4 a = g4[threadIdx.x];
  float4 b = g4[threadIdx.x + 256];
  float s  = a.x + a.y + a.z + a.w + b.x + b.y + b.z + b.w;
  float s2 = a.x * a.x + a.y * a.y + a.z * a.z + a.w * a.w +
             b.x * b.x + b.y * b.y + b.z * b.z + b.w * b.w;
#pragma unroll
  for (int o = 32; o > 0; o >>= 1) {
    s  += __shfl_down(s, o);
    s2 += __shfl_down(s2, o);
  }
  __shared__ float red[8];
  int wave = threadIdx.x >> 6;
  if ((threadIdx.x & 63) == 0) { red[wave] = s; red[wave + 4] = s2; }
  __syncthreads();
  if (threadIdx.x == 0) {
    float S  = red[0] + red[1] + red[2] + red[3];
    float S2 = red[4] + red[5] + red[6] + red[7];
    float mean = S * (1.0f / DH);
    float var  = S2 * (1.0f / DH) - mean * mean;  // ddof=0, matches jnp.var
    mv[row] = mean;
    rv[row] = rsqrtf(var + 1e-5f);
  }
}

// ---- kernel 2: normalize + scale + transpose + cast -> gateT[d][n] bf16 ---

__global__ __launch_bounds__(256) void norm_tr(const float* __restrict__ x,
                                               const float* __restrict__ mv,
                                               const float* __restrict__ rv,
                                               const float* __restrict__ lns,
                                               unsigned short* __restrict__ gateT) {
  __shared__ float tile[64][65];  // +1 pad: conflict-free transposed reads
  int d0 = blockIdx.x * 64;  // d-tile (0..2047)
  int n0 = blockIdx.y * 64;  // n-tile (0..4095)
#pragma unroll
  for (int i = 0; i < 16; i++) {
    int idx = threadIdx.x + i * 256;
    int r = idx >> 6, c = idx & 63;  // r = n offset, c = d offset (coalesced in c)
    float v = x[(size_t)(n0 + r) * (2 * DH) + DH + d0 + c];
    tile[r][c] = (v - mv[n0 + r]) * rv[n0 + r];
  }
  __syncthreads();
#pragma unroll
  for (int i = 0; i < 16; i++) {
    int idx = threadIdx.x + i * 256;
    int dr = idx >> 6, nc = idx & 63;  // coalesced in nc
    float v = tile[nc][dr] * lns[d0 + dr];
    gateT[(size_t)(d0 + dr) * SEQ + n0 + nc] = f2bf(v);
  }
}

// ---- kernel 3: tril-masked cast w fp32 -> bf16 ----------------------------

__global__ __launch_bounds__(256) void cast_w_tril(const float* __restrict__ w,
                                                   unsigned short* __restrict__ wb) {
  size_t e = ((size_t)blockIdx.x * 256 + threadIdx.x) * 8;
  int m = (int)(e >> 12);    // row (4096 = 2^12 cols)
  int k = (int)(e & 4095);   // col
  uint4 o;
  if (k + 7 <= m) {  // fully inside lower triangle
    const float4* s = (const float4*)(w + e);
    float4 a = s[0], b = s[1];
    o.x = (unsigned)f2bf(a.x) | ((unsigned)f2bf(a.y) << 16);
    o.y = (unsigned)f2bf(a.z) | ((unsigned)f2bf(a.w) << 16);
    o.z = (unsigned)f2bf(b.x) | ((unsigned)f2bf(b.y) << 16);
    o.w = (unsigned)f2bf(b.z) | ((unsigned)f2bf(b.w) << 16);
  } else if (k > m) {  // fully above diagonal: no read needed
    o.x = o.y = o.z = o.w = 0u;
  } else {  // straddles the diagonal
    unsigned short t[8];
#pragma unroll
    for (int j = 0; j < 8; j++) t[j] = (k + j <= m) ? f2bf(w[e + j]) : (unsigned short)0;
    o.x = (unsigned)t[0] | ((unsigned)t[1] << 16);
    o.y = (unsigned)t[2] | ((unsigned)t[3] << 16);
    o.z = (unsigned)t[4] | ((unsigned)t[5] << 16);
    o.w = (unsigned)t[6] | ((unsigned)t[7] << 16);
  }
  *(uint4*)(wb + e) = o;
}

// ---- kernel 4: transpose + cast proj_w -> projT[j][d] bf16 ----------------

__global__ __launch_bounds__(256) void proj_tr(const float* __restrict__ pw,
                                               unsigned short* __restrict__ pT) {
  __shared__ float tile[64][65];
  int j0 = blockIdx.x * 64;  // out-col tile (0..1023)
  int d0 = blockIdx.y * 64;  // d tile (0..2047)
#pragma unroll
  for (int i = 0; i < 16; i++) {
    int idx = threadIdx.x + i * 256;
    int r = idx >> 6, c = idx & 63;  // r = d offset, c = j offset
    tile[r][c] = pw[(size_t)(d0 + r) * DOUT + j0 + c];
  }
  __syncthreads();
#pragma unroll
  for (int i = 0; i < 16; i++) {
    int idx = threadIdx.x + i * 256;
    int jr = idx >> 6, dc = idx & 63;
    pT[(size_t)(j0 + jr) * DH + d0 + dc] = f2bf(tile[dc][jr]);
  }
}

// ---- MFMA GEMM, 64x64 tile, BK=64, COUNTED-VMCNT 2-deep pipeline ----------
// C = A(MxK) * BT(NxK)^T, bf16 in / fp32 acc. 256 threads = 4 waves (2x2);
// each wave owns a 32x32 subtile (2x2 16x16 acc frags), 8 MFMA + 8
// ds_read_b128 per wave per BK=64 step. Tile/grid config = round-0 best
// (64x64, 1024 uniform blocks, 3-4 blocks/CU resident).
//
// ROUND-3 LESSON: dbuf behind __syncthreads changes nothing — __syncthreads
// drains vmcnt(0), so the barrier still waits on the JUST-issued next-tile
// loads. Fix = T4 counted waits: per K-step
//     stage(buf^1)                      // 4 global_load_lds per thread
//     s_waitcnt vmcnt(4)                // waits only for stage(t) — issued
//                                       // one full compute-phase ago -> ~0 stall
//     s_barrier                         // all waves: buf fully staged
//     compute(buf)                      // ds_read + MFMA (compiler lgkmcnt's)
//     s_barrier                         // all waves done READING buf before
//                                       // next iter's stage overwrites it
// vmcnt is in-issue-order (m135), so vmcnt(4) = "the 4 loads of stage(t+1)
// may remain, everything older (stage(t)) is done". Only the last step and
// the prologue pay a full drain. All asm waits carry "memory" clobbers so
// neither the g2l16 calls nor the ds_reads can cross them.
//
// PAIR (GEMM1 causal): block p does row-blocks {p, 63-p} sequentially, each
// to its diagonal -> exactly 65 k-steps/block, perfectly uniform grid.
// A is pre-masked to tril so diagonal tiles are exact.
// EPI==1: P[m][n] = bf16( xfull[m][n] * (acc + rbias[m]) )
// EPI==2: out[m][n] = acc + cbias[n]
//
// LDS: 2 x (8KB A + 8KB B) = 32 KB. 128 B rows (BK=64 bf16) = 32 banks;
// XOR-8 chunk swizzle (data chunk c of row R at physical chunk c^(R&7)) ->
// conflict-free frag reads (0 SQ_LDS_BANK_CONFLICT, rounds 0-3).

template <int BM, int BN, int EPI, bool PAIR>
__global__ __launch_bounds__(256) void gemm_cnt(const unsigned short* __restrict__ A,
                                                const unsigned short* __restrict__ BT,
                                                const float* __restrict__ xfull,
                                                const float* __restrict__ rbias,
                                                unsigned short* __restrict__ Pout,
                                                const float* __restrict__ cbias,
                                                float* __restrict__ out,
                                                int N, int K) {
  constexpr int BK = 64;
  constexpr int MI = BM / 32;                    // acc frags per wave, rows
  constexpr int NJ = BN / 32;                    // acc frags per wave, cols
  constexpr int ARPT = (BM * BK) / (256 * 8);    // A 16B-chunks per thread
  constexpr int BRPT = (BN * BK) / (256 * 8);    // B 16B-chunks per thread
  constexpr int ASZ = BM * BK, BSZ = BN * BK;
  static_assert(ARPT + BRPT == 4, "vmcnt immediates assume 4 loads per stage");

  __shared__ unsigned short sA[2 * ASZ];
  __shared__ unsigned short sB[2 * BSZ];

  const int tid = threadIdx.x;
  const int lane = tid & 63, wave = tid >> 6;
  const int quad = lane >> 4, l16 = lane & 15;
  const int wm = wave >> 1, wn = wave & 1;
  const int bn0 = blockIdx.x * BN;

  const int nPass = PAIR ? 2 : 1;
  for (int pass = 0; pass < nPass; pass++) {
    const int by = PAIR ? (pass == 0 ? (int)blockIdx.y
                                     : (2 * (int)gridDim.y - 1 - (int)blockIdx.y))
                        : (int)blockIdx.y;
    const int bm0 = by * BM;
    const int nt = (PAIR ? (bm0 + BM) : K) / BK;  // uniform across the grid

    // staging source pointers (row/chunk swizzled), advance by BK per step
    const unsigned short* aP[ARPT];
    const unsigned short* bP[BRPT];
#pragma unroll
    for (int r = 0; r < ARPT; r++) {
      int idx = r * 256 + tid;
      int row = idx >> 3;
      int col = ((idx & 7) ^ (row & 7)) * 8;
      aP[r] = A + (size_t)(bm0 + row) * K + col;
    }
#pragma unroll
    for (int r = 0; r < BRPT; r++) {
      int idx = r * 256 + tid;
      int row = idx >> 3;
      int col = ((idx & 7) ^ (row & 7)) * 8;
      bP[r] = BT + (size_t)(bn0 + row) * K + col;
    }

    f32x4 acc[MI][NJ] = {};

    auto stage = [&](int buf) {
#pragma unroll
      for (int r = 0; r < ARPT; r++) {
        g2l16(aP[r], &sA[buf * ASZ + (r * 256 + tid) * 8]);
        aP[r] += BK;
      }
#pragma unroll
      for (int r = 0; r < BRPT; r++) {
        g2l16(bP[r], &sB[buf * BSZ + (r * 256 + tid) * 8]);
        bP[r] += BK;
      }
    };

    auto compute = [&](int buf) {
      const unsigned short* bA = &sA[buf * ASZ];
      const unsigned short* bB = &sB[buf * BSZ];
      bf16x8 af[2][MI], bfr[2][NJ];
#pragma unroll
      for (int h = 0; h < 2; h++) {
#pragma unroll
        for (int i = 0; i < MI; i++) {
          int R = wm * (BM / 2) + i * 16 + l16;
          af[h][i] = *(const bf16x8*)&bA[R * BK + (((h * 4 + quad) ^ (R & 7)) * 8)];
        }
#pragma unroll
        for (int j = 0; j < NJ; j++) {
          int R = wn * (BN / 2) + j * 16 + l16;
          bfr[h][j] = *(const bf16x8*)&bB[R * BK + (((h * 4 + quad) ^ (R & 7)) * 8)];
        }
      }
#pragma unroll
      for (int h = 0; h < 2; h++)
#pragma unroll
        for (int i = 0; i < MI; i++)
#pragma unroll
          for (int j = 0; j < NJ; j++)
            acc[i][j] = __builtin_amdgcn_mfma_f32_16x16x32_bf16(af[h][i], bfr[h][j], acc[i][j], 0, 0, 0);
    };

    if (pass) __builtin_amdgcn_s_barrier();  // prev pass LDS reads all done

    stage(0);
    int cur = 0;
    for (int t = 0; t < nt; t++) {
      if (t + 1 < nt) {
        stage(cur ^ 1);
        // wait only for stage(t) (4 oldest); stage(t+1)'s 4 may stay in flight.
        // epilogue/prologue VMEM remnants only make this MORE conservative.
        asm volatile("s_waitcnt vmcnt(4)" ::: "memory");
      } else {
        asm volatile("s_waitcnt vmcnt(0)" ::: "memory");
      }
      __builtin_amdgcn_s_barrier();   // buf `cur` fully staged, all waves
      compute(cur);
      __builtin_amdgcn_s_barrier();   // all waves done reading buf `cur`
      cur ^= 1;
    }

    // epilogue — C/D layout: col = lane&15, row = quad*4 + reg (m89-verified)
#pragma unroll
    for (int i = 0; i < MI; i++) {
#pragma unroll
      for (int j = 0; j < NJ; j++) {
        int col = bn0 + wn * (BN / 2) + j * 16 + l16;
#pragma unroll
        for (int r = 0; r < 4; r++) {
          int row = bm0 + wm * (BM / 2) + i * 16 + quad * 4 + r;
          float v = acc[i][j][r];
          if (EPI == 1) {
            float g = v + rbias[row];
            float pv = xfull[(size_t)row * (2 * DH) + col] * g;
            Pout[(size_t)row * N + col] = f2bf(pv);
          } else {
            out[(size_t)row * N + col] = v + cbias[col];
          }
        }
      }
    }
  }
}

// ---- launch ---------------------------------------------------------------

extern "C" void kernel_launch(void* const* d_in, const int* in_sizes, int n_in,
                              void* d_out, int out_size, void* d_ws, size_t ws_size,
                              hipStream_t stream) {
  (void)in_sizes; (void)n_in; (void)out_size; (void)ws_size;
  const float* x   = (const float*)d_in[0];
  const float* lns = (const float*)d_in[1];
  const float* w   = (const float*)d_in[2];
  const float* sb  = (const float*)d_in[3];
  const float* pw  = (const float*)d_in[4];
  const float* pb  = (const float*)d_in[5];
  float* out = (float*)d_out;

  char* p = (char*)d_ws;
  unsigned short* gateT = (unsigned short*)p; p += (size_t)DH * SEQ * 2;    // 16 MB
  unsigned short* wb    = (unsigned short*)p; p += (size_t)SEQ * SEQ * 2;   // 32 MB
  unsigned short* projT = (unsigned short*)p; p += (size_t)DOUT * DH * 2;   //  4 MB
  unsigned short* Pbuf  = (unsigned short*)p; p += (size_t)SEQ * DH * 2;    // 16 MB
  float* mv = (float*)p; p += (size_t)SEQ * 4;
  float* rv = (float*)p; p += (size_t)SEQ * 4;

  ln_stats<<<SEQ, 256, 0, stream>>>(x, mv, rv);
  norm_tr<<<dim3(DH / 64, SEQ / 64), 256, 0, stream>>>(x, mv, rv, lns, gateT);
  cast_w_tril<<<(int)(((size_t)SEQ * SEQ / 8) / 256), 256, 0, stream>>>(w, wb);
  proj_tr<<<dim3(DOUT / 64, DH / 64), 256, 0, stream>>>(pw, projT);

  // GEMM1: gate2 = tril(w) @ gate  (M=4096, N=2048, K=4096, causal)
  // 64x64 tiles, PAIR {p,63-p} -> 65 uniform k-steps/block,
  // grid (32,32)=1024 blocks, counted-vmcnt 2-deep pipeline.
  gemm_cnt<64, 64, 1, true><<<dim3(DH / 64, SEQ / 128), 256, 0, stream>>>(
      wb, gateT, x, sb, Pbuf, nullptr, nullptr, DH, SEQ);
  // GEMM2: out = P @ proj_w + proj_b  (M=4096, N=1024, K=2048)
  // 64x64 tiles, grid (16,64)=1024 blocks, 32 uniform k-steps.
  gemm_cnt<64, 64, 2, false><<<dim3(DOUT / 64, SEQ / 64), 256, 0, stream>>>(
      Pbuf, projT, nullptr, nullptr, nullptr, pb, out, DOUT, DH);
}

// Round 5
// 237.429 us; speedup vs baseline: 1.1316x; 1.0692x over previous
//
#include <hip/hip_runtime.h>
#include <cstdint>
#include <cstddef>

#define SEQ 4096
#define DH 2048
#define DOUT 1024

typedef float f32x4 __attribute__((ext_vector_type(4)));
typedef __bf16 bf16x8 __attribute__((ext_vector_type(8)));

// ---- helpers --------------------------------------------------------------

__device__ __forceinline__ unsigned short f2bf(float f) {
  // round-to-nearest-even fp32 -> bf16 (inputs are finite; no NaN handling)
  unsigned int u = __float_as_uint(f);
  unsigned int r = (u + 0x7FFFu + ((u >> 16) & 1u)) >> 16;
  return (unsigned short)r;
}

// fp32 -> OCP e4m3fn, RNE, saturate to 448. Software encode (no header dep).
__device__ __forceinline__ unsigned char f2f8(float f) {
  unsigned int u = __float_as_uint(f);
  unsigned int sign = (u >> 24) & 0x80u;
  float a = __uint_as_float(u & 0x7FFFFFFFu);
  if (a >= 448.f) return (unsigned char)(sign | 0x7Eu);   // max finite
  if (a < 0.015625f) {                                    // denormal/zero path
    int q = (int)rintf(a * 512.0f);                       // RNE to 2^-9 grid
    if (q == 8) return (unsigned char)(sign | 0x08u);     // carried to 2^-6
    return (unsigned char)(sign | (unsigned)q);
  }
  int e = (int)((u >> 23) & 0xFF) - 127;                  // e in [-6, 8]
  unsigned int m = u & 0x7FFFFFu;
  unsigned int m3 = (m + 0x7FFFFu + ((m >> 20) & 1u)) >> 20;  // RNE 23b->3b
  if (m3 == 8u) { m3 = 0u; e++; if (e > 8) return (unsigned char)(sign | 0x7Eu); }
  return (unsigned char)(sign | ((unsigned)(e + 7) << 3) | m3);
}

__device__ __forceinline__ void g2l16(const void* g, void* l) {
  // async global -> LDS, 16 bytes per lane. LDS side is wave-uniform base + lane*16.
  __builtin_amdgcn_global_load_lds((__attribute__((address_space(1))) void*)g,
                                   (__attribute__((address_space(3))) void*)l, 16, 0, 0);
}

#define W_SCALE 1048576.0f         // 2^20: lifts w (~2.4e-7) into e4m3 range
#define W_SCALE_INV (1.0f / 1048576.0f)

// ---- kernel 1: fused prepro (independent sections, one launch) ------------
// blocks [0,4096):        ln_stats  — per-row mean/rstd of gate half
// blocks [4096,8192):     w -> fp8 tril cast (scaled by 2^20), 16 elems/thread
// blocks [8192,8704):     proj_w transpose+cast -> projT[j][d] bf16
// Fusing removes 2 launch/drain gaps and lets sections co-fill the machine.

__global__ __launch_bounds__(256) void prep_all(const float* __restrict__ x,
                                                float* __restrict__ mv,
                                                float* __restrict__ rv,
                                                const float* __restrict__ w,
                                                unsigned char* __restrict__ wf8,
                                                const float* __restrict__ pw,
                                                unsigned short* __restrict__ pT) {
  int b = blockIdx.x;
  if (b < 4096) {
    // ---- ln_stats ----
    int row = b;
    const float4* g4 = (const float4*)(x + (size_t)row * (2 * DH) + DH);
    float4 a = g4[threadIdx.x];
    float4 bb = g4[threadIdx.x + 256];
    float s  = a.x + a.y + a.z + a.w + bb.x + bb.y + bb.z + bb.w;
    float s2 = a.x * a.x + a.y * a.y + a.z * a.z + a.w * a.w +
               bb.x * bb.x + bb.y * bb.y + bb.z * bb.z + bb.w * bb.w;
#pragma unroll
    for (int o = 32; o > 0; o >>= 1) {
      s  += __shfl_down(s, o);
      s2 += __shfl_down(s2, o);
    }
    __shared__ float red[8];
    int wave = threadIdx.x >> 6;
    if ((threadIdx.x & 63) == 0) { red[wave] = s; red[wave + 4] = s2; }
    __syncthreads();
    if (threadIdx.x == 0) {
      float S  = red[0] + red[1] + red[2] + red[3];
      float S2 = red[4] + red[5] + red[6] + red[7];
      float mean = S * (1.0f / DH);
      float var  = S2 * (1.0f / DH) - mean * mean;  // ddof=0, matches jnp.var
      mv[row] = mean;
      rv[row] = rsqrtf(var + 1e-5f);
    }
  } else if (b < 8192) {
    // ---- tril-masked w -> fp8 (x 2^20) ----
    size_t e = (((size_t)(b - 4096)) * 256 + threadIdx.x) * 16;
    int m = (int)(e >> 12);    // row (4096 cols)
    int k = (int)(e & 4095);   // col (16-aligned)
    uint4 o;
    if (k > m) {               // fully above diagonal
      o.x = o.y = o.z = o.w = 0u;
    } else {
      const float4* s4 = (const float4*)(w + e);
      float4 v0 = s4[0], v1 = s4[1], v2 = s4[2], v3 = s4[3];
      float vv[16] = {v0.x, v0.y, v0.z, v0.w, v1.x, v1.y, v1.z, v1.w,
                      v2.x, v2.y, v2.z, v2.w, v3.x, v3.y, v3.z, v3.w};
      unsigned char t[16];
#pragma unroll
      for (int j = 0; j < 16; j++)
        t[j] = (k + j <= m) ? f2f8(vv[j] * W_SCALE) : (unsigned char)0;
      o.x = (unsigned)t[0] | ((unsigned)t[1] << 8) | ((unsigned)t[2] << 16) | ((unsigned)t[3] << 24);
      o.y = (unsigned)t[4] | ((unsigned)t[5] << 8) | ((unsigned)t[6] << 16) | ((unsigned)t[7] << 24);
      o.z = (unsigned)t[8] | ((unsigned)t[9] << 8) | ((unsigned)t[10] << 16) | ((unsigned)t[11] << 24);
      o.w = (unsigned)t[12] | ((unsigned)t[13] << 8) | ((unsigned)t[14] << 16) | ((unsigned)t[15] << 24);
    }
    *(uint4*)(wf8 + e) = o;
  } else {
    // ---- proj_w transpose+cast -> projT[j][d] bf16 ----
    __shared__ float tile[64][65];
    int b2 = b - 8192;                 // [0,512)
    int j0 = (b2 & 15) * 64;           // out-col tile (0..1023)
    int d0 = (b2 >> 4) * 64;           // d tile (0..2047)
#pragma unroll
    for (int i = 0; i < 16; i++) {
      int idx = threadIdx.x + i * 256;
      int r = idx >> 6, c = idx & 63;  // r = d offset, c = j offset
      tile[r][c] = pw[(size_t)(d0 + r) * DOUT + j0 + c];
    }
    __syncthreads();
#pragma unroll
    for (int i = 0; i < 16; i++) {
      int idx = threadIdx.x + i * 256;
      int jr = idx >> 6, dc = idx & 63;
      pT[(size_t)(j0 + jr) * DH + d0 + dc] = f2bf(tile[dc][jr]);
    }
  }
}

// ---- kernel 2: normalize + scale + transpose + cast -> gf8T[d][n] fp8 -----
// 4 n per thread in the write phase -> 4 B stores (fp8 is 1 B/elem).

__global__ __launch_bounds__(256) void norm_tr8(const float* __restrict__ x,
                                                const float* __restrict__ mv,
                                                const float* __restrict__ rv,
                                                const float* __restrict__ lns,
                                                unsigned char* __restrict__ gf8T) {
  __shared__ float tile[64][65];  // +1 pad
  int d0 = blockIdx.x * 64;  // d-tile (0..2047)
  int n0 = blockIdx.y * 64;  // n-tile (0..4095)
#pragma unroll
  for (int i = 0; i < 16; i++) {
    int idx = threadIdx.x + i * 256;
    int r = idx >> 6, c = idx & 63;  // r = n offset, c = d offset (coalesced in c)
    float v = x[(size_t)(n0 + r) * (2 * DH) + DH + d0 + c];
    tile[r][c] = (v - mv[n0 + r]) * rv[n0 + r];
  }
  __syncthreads();
#pragma unroll
  for (int i = 0; i < 4; i++) {
    int idx = threadIdx.x + i * 256;   // [0,1024)
    int dr = idx >> 4;                 // d offset (0..63)
    int nq = idx & 15;                 // n quad (0..15)
    float sc = lns[d0 + dr];
    unsigned int pk = 0;
#pragma unroll
    for (int j = 0; j < 4; j++)
      pk |= (unsigned int)f2f8(tile[nq * 4 + j][dr] * sc) << (8 * j);
    *(unsigned int*)&gf8T[(size_t)(d0 + dr) * SEQ + n0 + nq * 4] = pk;
  }
}

// ---- GEMM1: fp8 MFMA, 64x64 tile, BK=128, counted-vmcnt 2-deep pipeline ---
// C[m,d] = sum_n w[m,n]*gate[n,d].  A = wf8[m][k] (tril, x2^20),
// BT = gf8T[d][k].  fp8 halves LDS traffic vs bf16 (round-4 arithmetic:
// 64^2 bf16 = 3.2 GB LDS -> 46us floor; fp8 -> 1.6 GB -> ~23us) at the SAME
// MFMA rate (16x16x32 fp8 = bf16 rate) and the SAME 128 B LDS row geometry
// (BK=128 fp8 = 128 B rows = 32 banks; XOR-8 16B-chunk swizzle unchanged,
// 0 bank conflicts measured rounds 0-4).
//
// PAIR causal: block p does row-blocks {p, 63-p}; kEnd rounds UP to BK=128
// (A is tril-pre-masked, so the overshoot k-range multiplies by zeros):
// nt = (by+2)>>1 -> per-block total exactly 33 steps, perfectly uniform.
// Epilogue: P[m][n] = bf16( xfull[m][n] * (acc*2^-20 + rbias[m]) ).

__global__ __launch_bounds__(256) void gemm_f8(const unsigned char* __restrict__ A,
                                               const unsigned char* __restrict__ BT,
                                               const float* __restrict__ xfull,
                                               const float* __restrict__ rbias,
                                               unsigned short* __restrict__ Pout) {
  constexpr int BK = 128;
  constexpr int ASZ = 64 * BK;   // 8 KB
  __shared__ unsigned char sA[2 * ASZ];
  __shared__ unsigned char sB[2 * ASZ];

  const int tid = threadIdx.x;
  const int lane = tid & 63, wave = tid >> 6;
  const int quad = lane >> 4, l16 = lane & 15;
  const int wm = wave >> 1, wn = wave & 1;
  const int bn0 = blockIdx.x * 64;
  const int K = SEQ;

  for (int pass = 0; pass < 2; pass++) {
    const int by = pass == 0 ? (int)blockIdx.y : 63 - (int)blockIdx.y;
    const int bm0 = by * 64;
    const int nt = (by + 2) >> 1;   // ceil(64*(by+1)/128); pair sums to 33

    // staging sources: idx -> row idx>>3, 16B chunk (idx&7)^(row&7)
    const unsigned char* aP[2];
    const unsigned char* bP[2];
#pragma unroll
    for (int r = 0; r < 2; r++) {
      int idx = r * 256 + tid;
      int row = idx >> 3;
      int col = ((idx & 7) ^ (row & 7)) * 16;
      aP[r] = A + (size_t)(bm0 + row) * K + col;
      bP[r] = BT + (size_t)(bn0 + row) * K + col;
    }

    f32x4 acc[2][2] = {};

    auto stage = [&](int buf) {
#pragma unroll
      for (int r = 0; r < 2; r++) {
        g2l16(aP[r], &sA[buf * ASZ + (r * 256 + tid) * 16]);
        aP[r] += BK;
      }
#pragma unroll
      for (int r = 0; r < 2; r++) {
        g2l16(bP[r], &sB[buf * ASZ + (r * 256 + tid) * 16]);
        bP[r] += BK;
      }
    };

    auto compute = [&](int buf) {
      const unsigned char* bA = &sA[buf * ASZ];
      const unsigned char* bB = &sB[buf * ASZ];
      long a8[4][2], b8[4][2];
#pragma unroll
      for (int h = 0; h < 4; h++) {
        // data byte offset in row = h*32 + quad*8; 16B chunk = h*2+(quad>>1)
        int cc = h * 2 + (quad >> 1), rem = (quad & 1) * 8;
#pragma unroll
        for (int i = 0; i < 2; i++) {
          int R = wm * 32 + i * 16 + l16;
          a8[h][i] = *(const long*)&bA[R * BK + ((cc ^ (R & 7)) * 16) + rem];
        }
#pragma unroll
        for (int j = 0; j < 2; j++) {
          int R = wn * 32 + j * 16 + l16;
          b8[h][j] = *(const long*)&bB[R * BK + ((cc ^ (R & 7)) * 16) + rem];
        }
      }
#pragma unroll
      for (int h = 0; h < 4; h++)
#pragma unroll
        for (int i = 0; i < 2; i++)
#pragma unroll
          for (int j = 0; j < 2; j++)
            acc[i][j] = __builtin_amdgcn_mfma_f32_16x16x32_fp8_fp8(a8[h][i], b8[h][j], acc[i][j], 0, 0, 0);
    };

    stage(0);
    int cur = 0;
    for (int t = 0; t < nt; t++) {
      if (t + 1 < nt) {
        stage(cur ^ 1);
        // wait only for stage(t) (4 oldest); stage(t+1)'s 4 stay in flight
        asm volatile("s_waitcnt vmcnt(4)" ::: "memory");
      } else {
        asm volatile("s_waitcnt vmcnt(0)" ::: "memory");
      }
      __builtin_amdgcn_s_barrier();   // buf `cur` fully staged
      compute(cur);
      __builtin_amdgcn_s_barrier();   // all waves done reading buf `cur`
      cur ^= 1;
    }

    // epilogue — C/D layout: col = lane&15, row = quad*4 + reg (m89-verified)
#pragma unroll
    for (int i = 0; i < 2; i++) {
#pragma unroll
      for (int j = 0; j < 2; j++) {
        int col = bn0 + wn * 32 + j * 16 + l16;
#pragma unroll
        for (int r = 0; r < 4; r++) {
          int row = bm0 + wm * 32 + i * 16 + quad * 4 + r;
          float g = acc[i][j][r] * W_SCALE_INV + rbias[row];
          float pv = xfull[(size_t)row * (2 * DH) + col] * g;
          Pout[(size_t)row * DH + col] = f2bf(pv);
        }
      }
    }
  }
}

// ---- GEMM2: bf16 MFMA, 64x64 tile, BK=64, counted-vmcnt (round-4 config) --
// out[m][n] = (P @ projT^T)[m][n] + cbias[n]. Stays bf16: its output IS the
// final result (fp8's 6% relative error would blow past the bf16-level
// absmax; GEMM1's output is a 1e-5 perturbation on bias=1, hence fp8-safe).

__global__ __launch_bounds__(256) void gemm_bf(const unsigned short* __restrict__ A,
                                               const unsigned short* __restrict__ BT,
                                               const float* __restrict__ cbias,
                                               float* __restrict__ out,
                                               int N, int K) {
  constexpr int BK = 64;
  constexpr int ASZ = 64 * BK;   // elems (8 KB)
  __shared__ unsigned short sA[2 * ASZ];
  __shared__ unsigned short sB[2 * ASZ];

  const int tid = threadIdx.x;
  const int lane = tid & 63, wave = tid >> 6;
  const int quad = lane >> 4, l16 = lane & 15;
  const int wm = wave >> 1, wn = wave & 1;
  const int bn0 = blockIdx.x * 64;
  const int bm0 = blockIdx.y * 64;
  const int nt = K / BK;

  const unsigned short* aP[2];
  const unsigned short* bP[2];
#pragma unroll
  for (int r = 0; r < 2; r++) {
    int idx = r * 256 + tid;
    int row = idx >> 3;
    int col = ((idx & 7) ^ (row & 7)) * 8;
    aP[r] = A + (size_t)(bm0 + row) * K + col;
    bP[r] = BT + (size_t)(bn0 + row) * K + col;
  }

  f32x4 acc[2][2] = {};

  auto stage = [&](int buf) {
#pragma unroll
    for (int r = 0; r < 2; r++) {
      g2l16(aP[r], &sA[buf * ASZ + (r * 256 + tid) * 8]);
      aP[r] += BK;
    }
#pragma unroll
    for (int r = 0; r < 2; r++) {
      g2l16(bP[r], &sB[buf * ASZ + (r * 256 + tid) * 8]);
      bP[r] += BK;
    }
  };

  auto compute = [&](int buf) {
    const unsigned short* bA = &sA[buf * ASZ];
    const unsigned short* bB = &sB[buf * ASZ];
    bf16x8 af[2][2], bfr[2][2];
#pragma unroll
    for (int h = 0; h < 2; h++) {
#pragma unroll
      for (int i = 0; i < 2; i++) {
        int R = wm * 32 + i * 16 + l16;
        af[h][i] = *(const bf16x8*)&bA[R * BK + (((h * 4 + quad) ^ (R & 7)) * 8)];
      }
#pragma unroll
      for (int j = 0; j < 2; j++) {
        int R = wn * 32 + j * 16 + l16;
        bfr[h][j] = *(const bf16x8*)&bB[R * BK + (((h * 4 + quad) ^ (R & 7)) * 8)];
      }
    }
#pragma unroll
    for (int h = 0; h < 2; h++)
#pragma unroll
      for (int i = 0; i < 2; i++)
#pragma unroll
        for (int j = 0; j < 2; j++)
          acc[i][j] = __builtin_amdgcn_mfma_f32_16x16x32_bf16(af[h][i], bfr[h][j], acc[i][j], 0, 0, 0);
  };

  stage(0);
  int cur = 0;
  for (int t = 0; t < nt; t++) {
    if (t + 1 < nt) {
      stage(cur ^ 1);
      asm volatile("s_waitcnt vmcnt(4)" ::: "memory");
    } else {
      asm volatile("s_waitcnt vmcnt(0)" ::: "memory");
    }
    __builtin_amdgcn_s_barrier();
    compute(cur);
    __builtin_amdgcn_s_barrier();
    cur ^= 1;
  }

#pragma unroll
  for (int i = 0; i < 2; i++) {
#pragma unroll
    for (int j = 0; j < 2; j++) {
      int col = bn0 + wn * 32 + j * 16 + l16;
#pragma unroll
      for (int r = 0; r < 4; r++) {
        int row = bm0 + wm * 32 + i * 16 + quad * 4 + r;
        out[(size_t)row * N + col] = acc[i][j][r] + cbias[col];
      }
    }
  }
}

// ---- launch ---------------------------------------------------------------

extern "C" void kernel_launch(void* const* d_in, const int* in_sizes, int n_in,
                              void* d_out, int out_size, void* d_ws, size_t ws_size,
                              hipStream_t stream) {
  (void)in_sizes; (void)n_in; (void)out_size; (void)ws_size;
  const float* x   = (const float*)d_in[0];
  const float* lns = (const float*)d_in[1];
  const float* w   = (const float*)d_in[2];
  const float* sb  = (const float*)d_in[3];
  const float* pw  = (const float*)d_in[4];
  const float* pb  = (const float*)d_in[5];
  float* out = (float*)d_out;

  char* p = (char*)d_ws;
  unsigned char*  wf8   = (unsigned char*)p;  p += (size_t)SEQ * SEQ;        // 16 MB
  unsigned char*  gf8T  = (unsigned char*)p;  p += (size_t)DH * SEQ;         //  8 MB
  unsigned short* projT = (unsigned short*)p; p += (size_t)DOUT * DH * 2;    //  4 MB
  unsigned short* Pbuf  = (unsigned short*)p; p += (size_t)SEQ * DH * 2;     // 16 MB
  float* mv = (float*)p; p += (size_t)SEQ * 4;
  float* rv = (float*)p; p += (size_t)SEQ * 4;

  // prepro: 2 launches (was 4). Sections: ln_stats | w->fp8 tril | proj_tr.
  prep_all<<<4096 + 4096 + 512, 256, 0, stream>>>(x, mv, rv, w, wf8, pw, projT);
  norm_tr8<<<dim3(DH / 64, SEQ / 64), 256, 0, stream>>>(x, mv, rv, lns, gf8T);

  // GEMM1 (fp8): gate2 = tril(w) @ gate  (M=4096, N=2048, K=4096, causal)
  // 64x64 tiles BK=128, PAIR {p,63-p} -> 33 uniform k-steps/block,
  // grid (32,32)=1024 blocks, counted-vmcnt 2-deep pipeline.
  gemm_f8<<<dim3(DH / 64, SEQ / 128), 256, 0, stream>>>(wf8, gf8T, x, sb, Pbuf);

  // GEMM2 (bf16): out = P @ proj_w + proj_b  (M=4096, N=1024, K=2048)
  // 64x64 tiles BK=64, grid (16,64)=1024 blocks, 32 uniform k-steps.
  gemm_bf<<<dim3(DOUT / 64, SEQ / 64), 256, 0, stream>>>(Pbuf, projT, pb, out, DOUT, DH);
}

// Round 6
// 232.599 us; speedup vs baseline: 1.1551x; 1.0208x over previous
//
#include <hip/hip_runtime.h>
#include <cstdint>
#include <cstddef>

#define SEQ 4096
#define DH 2048
#define DOUT 1024

typedef float f32x4 __attribute__((ext_vector_type(4)));
typedef __bf16 bf16x8 __attribute__((ext_vector_type(8)));
typedef long longx2 __attribute__((ext_vector_type(2)));

// ---- helpers --------------------------------------------------------------

__device__ __forceinline__ unsigned short f2bf(float f) {
  // round-to-nearest-even fp32 -> bf16 (inputs are finite; no NaN handling)
  unsigned int u = __float_as_uint(f);
  unsigned int r = (u + 0x7FFFu + ((u >> 16) & 1u)) >> 16;
  return (unsigned short)r;
}

// fp32 -> OCP e4m3fn, RNE, saturate to 448. Software encode (no header dep).
__device__ __forceinline__ unsigned char f2f8(float f) {
  unsigned int u = __float_as_uint(f);
  unsigned int sign = (u >> 24) & 0x80u;
  float a = __uint_as_float(u & 0x7FFFFFFFu);
  if (a >= 448.f) return (unsigned char)(sign | 0x7Eu);   // max finite
  if (a < 0.015625f) {                                    // denormal/zero path
    int q = (int)rintf(a * 512.0f);                       // RNE to 2^-9 grid
    if (q == 8) return (unsigned char)(sign | 0x08u);     // carried to 2^-6
    return (unsigned char)(sign | (unsigned)q);
  }
  int e = (int)((u >> 23) & 0xFF) - 127;                  // e in [-6, 8]
  unsigned int m = u & 0x7FFFFFu;
  unsigned int m3 = (m + 0x7FFFFu + ((m >> 20) & 1u)) >> 20;  // RNE 23b->3b
  if (m3 == 8u) { m3 = 0u; e++; if (e > 8) return (unsigned char)(sign | 0x7Eu); }
  return (unsigned char)(sign | ((unsigned)(e + 7) << 3) | m3);
}

__device__ __forceinline__ void g2l16(const void* g, void* l) {
  // async global -> LDS, 16 bytes per lane. LDS side is wave-uniform base + lane*16.
  __builtin_amdgcn_global_load_lds((__attribute__((address_space(1))) void*)g,
                                   (__attribute__((address_space(3))) void*)l, 16, 0, 0);
}

#define W_SCALE 1048576.0f         // 2^20: lifts w (~2.4e-7) into e4m3 range
#define W_SCALE_INV (1.0f / 1048576.0f)

// ---- kernel 1: fused prepro (independent sections, one launch) ------------
// blocks [0,4096):        ln_stats  — per-row mean/rstd of gate half
// blocks [4096,8192):     w -> fp8 tril cast (scaled by 2^20), 16 elems/thread
// blocks [8192,8704):     proj_w transpose+cast -> projT[j][d] bf16

__global__ __launch_bounds__(256) void prep_all(const float* __restrict__ x,
                                                float* __restrict__ mv,
                                                float* __restrict__ rv,
                                                const float* __restrict__ w,
                                                unsigned char* __restrict__ wf8,
                                                const float* __restrict__ pw,
                                                unsigned short* __restrict__ pT) {
  int b = blockIdx.x;
  if (b < 4096) {
    // ---- ln_stats ----
    int row = b;
    const float4* g4 = (const float4*)(x + (size_t)row * (2 * DH) + DH);
    float4 a = g4[threadIdx.x];
    float4 bb = g4[threadIdx.x + 256];
    float s  = a.x + a.y + a.z + a.w + bb.x + bb.y + bb.z + bb.w;
    float s2 = a.x * a.x + a.y * a.y + a.z * a.z + a.w * a.w +
               bb.x * bb.x + bb.y * bb.y + bb.z * bb.z + bb.w * bb.w;
#pragma unroll
    for (int o = 32; o > 0; o >>= 1) {
      s  += __shfl_down(s, o);
      s2 += __shfl_down(s2, o);
    }
    __shared__ float red[8];
    int wave = threadIdx.x >> 6;
    if ((threadIdx.x & 63) == 0) { red[wave] = s; red[wave + 4] = s2; }
    __syncthreads();
    if (threadIdx.x == 0) {
      float S  = red[0] + red[1] + red[2] + red[3];
      float S2 = red[4] + red[5] + red[6] + red[7];
      float mean = S * (1.0f / DH);
      float var  = S2 * (1.0f / DH) - mean * mean;  // ddof=0, matches jnp.var
      mv[row] = mean;
      rv[row] = rsqrtf(var + 1e-5f);
    }
  } else if (b < 8192) {
    // ---- tril-masked w -> fp8 (x 2^20) ----
    size_t e = (((size_t)(b - 4096)) * 256 + threadIdx.x) * 16;
    int m = (int)(e >> 12);    // row (4096 cols)
    int k = (int)(e & 4095);   // col (16-aligned)
    uint4 o;
    if (k > m) {               // fully above diagonal
      o.x = o.y = o.z = o.w = 0u;
    } else {
      const float4* s4 = (const float4*)(w + e);
      float4 v0 = s4[0], v1 = s4[1], v2 = s4[2], v3 = s4[3];
      float vv[16] = {v0.x, v0.y, v0.z, v0.w, v1.x, v1.y, v1.z, v1.w,
                      v2.x, v2.y, v2.z, v2.w, v3.x, v3.y, v3.z, v3.w};
      unsigned char t[16];
#pragma unroll
      for (int j = 0; j < 16; j++)
        t[j] = (k + j <= m) ? f2f8(vv[j] * W_SCALE) : (unsigned char)0;
      o.x = (unsigned)t[0] | ((unsigned)t[1] << 8) | ((unsigned)t[2] << 16) | ((unsigned)t[3] << 24);
      o.y = (unsigned)t[4] | ((unsigned)t[5] << 8) | ((unsigned)t[6] << 16) | ((unsigned)t[7] << 24);
      o.z = (unsigned)t[8] | ((unsigned)t[9] << 8) | ((unsigned)t[10] << 16) | ((unsigned)t[11] << 24);
      o.w = (unsigned)t[12] | ((unsigned)t[13] << 8) | ((unsigned)t[14] << 16) | ((unsigned)t[15] << 24);
    }
    *(uint4*)(wf8 + e) = o;
  } else {
    // ---- proj_w transpose+cast -> projT[j][d] bf16 ----
    __shared__ float tile[64][65];
    int b2 = b - 8192;                 // [0,512)
    int j0 = (b2 & 15) * 64;           // out-col tile (0..1023)
    int d0 = (b2 >> 4) * 64;           // d tile (0..2047)
#pragma unroll
    for (int i = 0; i < 16; i++) {
      int idx = threadIdx.x + i * 256;
      int r = idx >> 6, c = idx & 63;  // r = d offset, c = j offset
      tile[r][c] = pw[(size_t)(d0 + r) * DOUT + j0 + c];
    }
    __syncthreads();
#pragma unroll
    for (int i = 0; i < 16; i++) {
      int idx = threadIdx.x + i * 256;
      int jr = idx >> 6, dc = idx & 63;
      pT[(size_t)(j0 + jr) * DH + d0 + dc] = f2bf(tile[dc][jr]);
    }
  }
}

// ---- kernel 2: normalize + scale + transpose + cast -> gf8T[d][n] fp8 -----

__global__ __launch_bounds__(256) void norm_tr8(const float* __restrict__ x,
                                                const float* __restrict__ mv,
                                                const float* __restrict__ rv,
                                                const float* __restrict__ lns,
                                                unsigned char* __restrict__ gf8T) {
  __shared__ float tile[64][65];  // +1 pad
  int d0 = blockIdx.x * 64;  // d-tile (0..2047)
  int n0 = blockIdx.y * 64;  // n-tile (0..4095)
#pragma unroll
  for (int i = 0; i < 16; i++) {
    int idx = threadIdx.x + i * 256;
    int r = idx >> 6, c = idx & 63;  // r = n offset, c = d offset (coalesced in c)
    float v = x[(size_t)(n0 + r) * (2 * DH) + DH + d0 + c];
    tile[r][c] = (v - mv[n0 + r]) * rv[n0 + r];
  }
  __syncthreads();
#pragma unroll
  for (int i = 0; i < 4; i++) {
    int idx = threadIdx.x + i * 256;   // [0,1024)
    int dr = idx >> 4;                 // d offset (0..63)
    int nq = idx & 15;                 // n quad (0..15)
    float sc = lns[d0 + dr];
    unsigned int pk = 0;
#pragma unroll
    for (int j = 0; j < 4; j++)
      pk |= (unsigned int)f2f8(tile[nq * 4 + j][dr] * sc) << (8 * j);
    *(unsigned int*)&gf8T[(size_t)(d0 + dr) * SEQ + n0 + nq * 4] = pk;
  }
}

// ---- GEMM1: fp8 MFMA, 64x64 tile, BK=128, counted-vmcnt 2-deep pipeline ---
// C[m,d] = sum_n w[m,n]*gate[n,d].  A = wf8[m][k] (tril, x2^20),
// BT = gf8T[d][k].
//
// ROUND-5 LESSON: b64 fragment reads (2 quads sharing each 16B chunk) cost
// exactly 4 conflict-cycles per ds_read_b64 (8.65M total ~ 14us on the LDS
// pipe, the binding resource). Fix: K-PERMUTED b128 reads. MFMA K-order is
// free as long as A and B use the SAME permutation, so each lane reads FULL
// 16B chunks (the access shape that measured 0 conflicts in all bf16
// rounds): lane quad q reads data chunks q and q+4; MFMA h in {0,1,2,3}
// consumes {X.lo, X.hi, Y.lo, Y.hi} = k-bytes {16q..+8}, {16q+8..+8},
// {64+16q..+8}, {64+16q+8..+8}. Per h the 4 quads cover 32 distinct bytes;
// identical mapping on A and B => same dot product. 8 b128 replace 16 b64.
//
// XCD swizzle (T1): 1D grid 1024, sw = (lin&7)*128 + lin>>3 (bijective);
// bx = sw>>5 -> each XCD keeps 4 B-tiles (1MB) L2-resident.
//
// PAIR causal: block does row-blocks {by0, 63-by0}; kEnd rounds UP to
// BK=128 (A is tril-pre-masked -> overshoot multiplies zeros);
// nt = (by+2)>>1 -> pair sums to 33 steps, perfectly uniform.
// Epilogue: P[m][n] = bf16( xfull[m][n] * (acc*2^-20 + rbias[m]) ).

__global__ __launch_bounds__(256) void gemm_f8(const unsigned char* __restrict__ A,
                                               const unsigned char* __restrict__ BT,
                                               const float* __restrict__ xfull,
                                               const float* __restrict__ rbias,
                                               unsigned short* __restrict__ Pout) {
  constexpr int BK = 128;
  constexpr int ASZ = 64 * BK;   // 8 KB
  __shared__ unsigned char sA[2 * ASZ];
  __shared__ unsigned char sB[2 * ASZ];

  const int tid = threadIdx.x;
  const int lane = tid & 63, wave = tid >> 6;
  const int quad = lane >> 4, l16 = lane & 15;
  const int wm = wave >> 1, wn = wave & 1;
  const int K = SEQ;

  const int lin = blockIdx.x;
  const int sw = ((lin & 7) << 7) | (lin >> 3);  // chunked XCD swizzle
  const int bn0 = (sw >> 5) * 64;                // d-tile, confined per XCD
  const int by0 = sw & 31;                       // m-pair id

  for (int pass = 0; pass < 2; pass++) {
    const int by = pass == 0 ? by0 : 63 - by0;
    const int bm0 = by * 64;
    const int nt = (by + 2) >> 1;   // ceil(64*(by+1)/128); pair sums to 33

    // staging sources: idx -> row idx>>3, 16B chunk (idx&7)^(row&7)
    const unsigned char* aP[2];
    const unsigned char* bP[2];
#pragma unroll
    for (int r = 0; r < 2; r++) {
      int idx = r * 256 + tid;
      int row = idx >> 3;
      int col = ((idx & 7) ^ (row & 7)) * 16;
      aP[r] = A + (size_t)(bm0 + row) * K + col;
      bP[r] = BT + (size_t)(bn0 + row) * K + col;
    }

    f32x4 acc[2][2] = {};

    auto stage = [&](int buf) {
#pragma unroll
      for (int r = 0; r < 2; r++) {
        g2l16(aP[r], &sA[buf * ASZ + (r * 256 + tid) * 16]);
        aP[r] += BK;
      }
#pragma unroll
      for (int r = 0; r < 2; r++) {
        g2l16(bP[r], &sB[buf * ASZ + (r * 256 + tid) * 16]);
        bP[r] += BK;
      }
    };

    auto compute = [&](int buf) {
      const unsigned char* bA = &sA[buf * ASZ];
      const unsigned char* bB = &sB[buf * ASZ];
      long a8[4][2], b8[4][2];
#pragma unroll
      for (int i = 0; i < 2; i++) {
        int R = wm * 32 + i * 16 + l16;
        const unsigned char* rowp = &bA[R * BK];
        int s = R & 7;
        longx2 X = *(const longx2*)&rowp[(quad ^ s) * 16];
        longx2 Y = *(const longx2*)&rowp[((quad + 4) ^ s) * 16];
        a8[0][i] = X[0]; a8[1][i] = X[1]; a8[2][i] = Y[0]; a8[3][i] = Y[1];
      }
#pragma unroll
      for (int j = 0; j < 2; j++) {
        int R = wn * 32 + j * 16 + l16;
        const unsigned char* rowp = &bB[R * BK];
        int s = R & 7;
        longx2 X = *(const longx2*)&rowp[(quad ^ s) * 16];
        longx2 Y = *(const longx2*)&rowp[((quad + 4) ^ s) * 16];
        b8[0][j] = X[0]; b8[1][j] = X[1]; b8[2][j] = Y[0]; b8[3][j] = Y[1];
      }
#pragma unroll
      for (int h = 0; h < 4; h++)
#pragma unroll
        for (int i = 0; i < 2; i++)
#pragma unroll
          for (int j = 0; j < 2; j++)
            acc[i][j] = __builtin_amdgcn_mfma_f32_16x16x32_fp8_fp8(a8[h][i], b8[h][j], acc[i][j], 0, 0, 0);
    };

    stage(0);
    int cur = 0;
    for (int t = 0; t < nt; t++) {
      if (t + 1 < nt) {
        stage(cur ^ 1);
        // wait only for stage(t) (4 oldest); stage(t+1)'s 4 stay in flight
        asm volatile("s_waitcnt vmcnt(4)" ::: "memory");
      } else {
        asm volatile("s_waitcnt vmcnt(0)" ::: "memory");
      }
      __builtin_amdgcn_s_barrier();   // buf `cur` fully staged
      compute(cur);
      __builtin_amdgcn_s_barrier();   // all waves done reading buf `cur`
      cur ^= 1;
    }

    // epilogue — C/D layout: col = lane&15, row = quad*4 + reg (m89-verified)
#pragma unroll
    for (int i = 0; i < 2; i++) {
#pragma unroll
      for (int j = 0; j < 2; j++) {
        int col = bn0 + wn * 32 + j * 16 + l16;
#pragma unroll
        for (int r = 0; r < 4; r++) {
          int row = bm0 + wm * 32 + i * 16 + quad * 4 + r;
          float g = acc[i][j][r] * W_SCALE_INV + rbias[row];
          float pv = xfull[(size_t)row * (2 * DH) + col] * g;
          Pout[(size_t)row * DH + col] = f2bf(pv);
        }
      }
    }
  }
}

// ---- GEMM2: bf16 MFMA, 64x64 tile, BK=64, counted-vmcnt -------------------
// out[m][n] = (P @ projT^T)[m][n] + cbias[n]. Stays bf16 (output feeds the
// final result directly; fp8 error would blow the tolerance).
// XCD swizzle: 1D grid 1024, sw = (lin&7)*128 + lin>>3; by = sw>>4 -> each
// XCD confined to 8 m-tiles: its P slice (2MB) goes L2-resident instead of
// streaming ~256MB of refetch from L3 (P is read by all 16 bx otherwise).

__global__ __launch_bounds__(256) void gemm_bf(const unsigned short* __restrict__ A,
                                               const unsigned short* __restrict__ BT,
                                               const float* __restrict__ cbias,
                                               float* __restrict__ out,
                                               int N, int K) {
  constexpr int BK = 64;
  constexpr int ASZ = 64 * BK;   // elems (8 KB)
  __shared__ unsigned short sA[2 * ASZ];
  __shared__ unsigned short sB[2 * ASZ];

  const int tid = threadIdx.x;
  const int lane = tid & 63, wave = tid >> 6;
  const int quad = lane >> 4, l16 = lane & 15;
  const int wm = wave >> 1, wn = wave & 1;

  const int lin = blockIdx.x;
  const int sw = ((lin & 7) << 7) | (lin >> 3);  // chunked XCD swizzle
  const int bn0 = (sw & 15) * 64;
  const int bm0 = (sw >> 4) * 64;                // m-tile, confined per XCD
  const int nt = K / BK;

  const unsigned short* aP[2];
  const unsigned short* bP[2];
#pragma unroll
  for (int r = 0; r < 2; r++) {
    int idx = r * 256 + tid;
    int row = idx >> 3;
    int col = ((idx & 7) ^ (row & 7)) * 8;
    aP[r] = A + (size_t)(bm0 + row) * K + col;
    bP[r] = BT + (size_t)(bn0 + row) * K + col;
  }

  f32x4 acc[2][2] = {};

  auto stage = [&](int buf) {
#pragma unroll
    for (int r = 0; r < 2; r++) {
      g2l16(aP[r], &sA[buf * ASZ + (r * 256 + tid) * 8]);
      aP[r] += BK;
    }
#pragma unroll
    for (int r = 0; r < 2; r++) {
      g2l16(bP[r], &sB[buf * ASZ + (r * 256 + tid) * 8]);
      bP[r] += BK;
    }
  };

  auto compute = [&](int buf) {
    const unsigned short* bA = &sA[buf * ASZ];
    const unsigned short* bB = &sB[buf * ASZ];
    bf16x8 af[2][2], bfr[2][2];
#pragma unroll
    for (int h = 0; h < 2; h++) {
#pragma unroll
      for (int i = 0; i < 2; i++) {
        int R = wm * 32 + i * 16 + l16;
        af[h][i] = *(const bf16x8*)&bA[R * BK + (((h * 4 + quad) ^ (R & 7)) * 8)];
      }
#pragma unroll
      for (int j = 0; j < 2; j++) {
        int R = wn * 32 + j * 16 + l16;
        bfr[h][j] = *(const bf16x8*)&bB[R * BK + (((h * 4 + quad) ^ (R & 7)) * 8)];
      }
    }
#pragma unroll
    for (int h = 0; h < 2; h++)
#pragma unroll
      for (int i = 0; i < 2; i++)
#pragma unroll
        for (int j = 0; j < 2; j++)
          acc[i][j] = __builtin_amdgcn_mfma_f32_16x16x32_bf16(af[h][i], bfr[h][j], acc[i][j], 0, 0, 0);
  };

  stage(0);
  int cur = 0;
  for (int t = 0; t < nt; t++) {
    if (t + 1 < nt) {
      stage(cur ^ 1);
      asm volatile("s_waitcnt vmcnt(4)" ::: "memory");
    } else {
      asm volatile("s_waitcnt vmcnt(0)" ::: "memory");
    }
    __builtin_amdgcn_s_barrier();
    compute(cur);
    __builtin_amdgcn_s_barrier();
    cur ^= 1;
  }

#pragma unroll
  for (int i = 0; i < 2; i++) {
#pragma unroll
    for (int j = 0; j < 2; j++) {
      int col = bn0 + wn * 32 + j * 16 + l16;
#pragma unroll
      for (int r = 0; r < 4; r++) {
        int row = bm0 + wm * 32 + i * 16 + quad * 4 + r;
        out[(size_t)row * N + col] = acc[i][j][r] + cbias[col];
      }
    }
  }
}

// ---- launch ---------------------------------------------------------------

extern "C" void kernel_launch(void* const* d_in, const int* in_sizes, int n_in,
                              void* d_out, int out_size, void* d_ws, size_t ws_size,
                              hipStream_t stream) {
  (void)in_sizes; (void)n_in; (void)out_size; (void)ws_size;
  const float* x   = (const float*)d_in[0];
  const float* lns = (const float*)d_in[1];
  const float* w   = (const float*)d_in[2];
  const float* sb  = (const float*)d_in[3];
  const float* pw  = (const float*)d_in[4];
  const float* pb  = (const float*)d_in[5];
  float* out = (float*)d_out;

  char* p = (char*)d_ws;
  unsigned char*  wf8   = (unsigned char*)p;  p += (size_t)SEQ * SEQ;        // 16 MB
  unsigned char*  gf8T  = (unsigned char*)p;  p += (size_t)DH * SEQ;         //  8 MB
  unsigned short* projT = (unsigned short*)p; p += (size_t)DOUT * DH * 2;    //  4 MB
  unsigned short* Pbuf  = (unsigned short*)p; p += (size_t)SEQ * DH * 2;     // 16 MB
  float* mv = (float*)p; p += (size_t)SEQ * 4;
  float* rv = (float*)p; p += (size_t)SEQ * 4;

  // prepro: 2 launches. Sections: ln_stats | w->fp8 tril | proj_tr.
  prep_all<<<4096 + 4096 + 512, 256, 0, stream>>>(x, mv, rv, w, wf8, pw, projT);
  norm_tr8<<<dim3(DH / 64, SEQ / 64), 256, 0, stream>>>(x, mv, rv, lns, gf8T);

  // GEMM1 (fp8): gate2 = tril(w) @ gate  (M=4096, N=2048, K=4096, causal)
  // 64x64 tiles BK=128, PAIR {p,63-p} -> 33 uniform k-steps, 1024 blocks,
  // K-permuted b128 fragment reads (conflict-free), XCD-chunked swizzle.
  gemm_f8<<<1024, 256, 0, stream>>>(wf8, gf8T, x, sb, Pbuf);

  // GEMM2 (bf16): out = P @ proj_w + proj_b  (M=4096, N=1024, K=2048)
  // 64x64 tiles BK=64, 1024 blocks, XCD-chunked swizzle (P slice L2-resident).
  gemm_bf<<<1024, 256, 0, stream>>>(Pbuf, projT, pb, out, DOUT, DH);
}

// Round 7
// 224.145 us; speedup vs baseline: 1.1987x; 1.0377x over previous
//
#include <hip/hip_runtime.h>
#include <cstdint>
#include <cstddef>

#define SEQ 4096
#define DH 2048
#define DOUT 1024

typedef float f32x4 __attribute__((ext_vector_type(4)));
typedef __bf16 bf16x8 __attribute__((ext_vector_type(8)));
typedef long longx2 __attribute__((ext_vector_type(2)));

// ---- helpers --------------------------------------------------------------

__device__ __forceinline__ unsigned short f2bf(float f) {
  // round-to-nearest-even fp32 -> bf16 (inputs are finite; no NaN handling)
  unsigned int u = __float_as_uint(f);
  unsigned int r = (u + 0x7FFFu + ((u >> 16) & 1u)) >> 16;
  return (unsigned short)r;
}

// fp32 -> OCP e4m3fn, RNE, saturate. Software fallback (used only if the HW
// builtin is unavailable).
__device__ __forceinline__ unsigned char f2f8_sw(float f) {
  unsigned int u = __float_as_uint(f);
  unsigned int sign = (u >> 24) & 0x80u;
  float a = __uint_as_float(u & 0x7FFFFFFFu);
  if (a >= 448.f) return (unsigned char)(sign | 0x7Eu);
  if (a < 0.015625f) {
    int q = (int)rintf(a * 512.0f);
    if (q == 8) return (unsigned char)(sign | 0x08u);
    return (unsigned char)(sign | (unsigned)q);
  }
  int e = (int)((u >> 23) & 0xFF) - 127;
  unsigned int m = u & 0x7FFFFFu;
  unsigned int m3 = (m + 0x7FFFFu + ((m >> 20) & 1u)) >> 20;
  if (m3 == 8u) { m3 = 0u; e++; if (e > 8) return (unsigned char)(sign | 0x7Eu); }
  return (unsigned char)(sign | ((unsigned)(e + 7) << 3) | m3);
}

// pack 4 fp32 -> 4 fp8 bytes. HW path: 2x v_cvt_pk_fp8_f32 (round-6 lesson:
// the ~20-op software encoder dominates prep VALU at 72M elements).
__device__ __forceinline__ unsigned int pk4_f8(float a, float b, float c, float d) {
#if __has_builtin(__builtin_amdgcn_cvt_pk_fp8_f32)
  int r = __builtin_amdgcn_cvt_pk_fp8_f32(a, b, 0, false);   // low word
  r = __builtin_amdgcn_cvt_pk_fp8_f32(c, d, r, true);        // high word
  return (unsigned int)r;
#else
  return (unsigned)f2f8_sw(a) | ((unsigned)f2f8_sw(b) << 8) |
         ((unsigned)f2f8_sw(c) << 16) | ((unsigned)f2f8_sw(d) << 24);
#endif
}

__device__ __forceinline__ void g2l16(const void* g, void* l) {
  // async global -> LDS, 16 bytes per lane. LDS side is wave-uniform base + lane*16.
  __builtin_amdgcn_global_load_lds((__attribute__((address_space(1))) void*)g,
                                   (__attribute__((address_space(3))) void*)l, 16, 0, 0);
}

#define W_SCALE 1048576.0f         // 2^20: lifts w (~2.4e-7) into e4m3 range
#define W_SCALE_INV (1.0f / 1048576.0f)

// ---- kernel 1: per-row mean / rstd of gate half ---------------------------
// Runs alone first: mv/rv gate the norm section of prep2.

__global__ __launch_bounds__(256) void ln_stats(const float* __restrict__ x,
                                                float* __restrict__ mv,
                                                float* __restrict__ rv) {
  int row = blockIdx.x;
  const float4* g4 = (const float4*)(x + (size_t)row * (2 * DH) + DH);
  float4 a = g4[threadIdx.x];
  float4 b = g4[threadIdx.x + 256];
  float s  = a.x + a.y + a.z + a.w + b.x + b.y + b.z + b.w;
  float s2 = a.x * a.x + a.y * a.y + a.z * a.z + a.w * a.w +
             b.x * b.x + b.y * b.y + b.z * b.z + b.w * b.w;
#pragma unroll
  for (int o = 32; o > 0; o >>= 1) {
    s  += __shfl_down(s, o);
    s2 += __shfl_down(s2, o);
  }
  __shared__ float red[8];
  int wave = threadIdx.x >> 6;
  if ((threadIdx.x & 63) == 0) { red[wave] = s; red[wave + 4] = s2; }
  __syncthreads();
  if (threadIdx.x == 0) {
    float S  = red[0] + red[1] + red[2] + red[3];
    float S2 = red[4] + red[5] + red[6] + red[7];
    float mean = S * (1.0f / DH);
    float var  = S2 * (1.0f / DH) - mean * mean;  // ddof=0, matches jnp.var
    mv[row] = mean;
    rv[row] = rsqrtf(var + 1e-5f);
  }
}

// ---- kernel 2: fused prep (independent sections co-fill the machine) ------
// blocks [0,2048):        norm+transpose+fp8 -> gf8T[d][n]
// blocks [2048,6144):     w -> fp8 tril cast (x 2^20), 16 elems/thread
// blocks [6144,6656):     proj_w transpose+cast -> projT[j][d] bf16

__global__ __launch_bounds__(256) void prep2(const float* __restrict__ x,
                                             const float* __restrict__ mv,
                                             const float* __restrict__ rv,
                                             const float* __restrict__ lns,
                                             unsigned char* __restrict__ gf8T,
                                             const float* __restrict__ w,
                                             unsigned char* __restrict__ wf8,
                                             const float* __restrict__ pw,
                                             unsigned short* __restrict__ pT) {
  int b = blockIdx.x;
  if (b < 2048) {
    // ---- normalize + scale + transpose + fp8 ----
    __shared__ float tile[64][65];  // +1 pad
    int d0 = (b & 31) * 64;         // d-tile (0..2047)
    int n0 = (b >> 5) * 64;         // n-tile (0..4095)
#pragma unroll
    for (int i = 0; i < 16; i++) {
      int idx = threadIdx.x + i * 256;
      int r = idx >> 6, c = idx & 63;  // r = n offset, c = d offset (coalesced in c)
      float v = x[(size_t)(n0 + r) * (2 * DH) + DH + d0 + c];
      tile[r][c] = (v - mv[n0 + r]) * rv[n0 + r];
    }
    __syncthreads();
#pragma unroll
    for (int i = 0; i < 4; i++) {
      int idx = threadIdx.x + i * 256;   // [0,1024)
      int dr = idx >> 4;                 // d offset (0..63)
      int nq = idx & 15;                 // n quad (0..15)
      float sc = lns[d0 + dr];
      unsigned int pk = pk4_f8(tile[nq * 4 + 0][dr] * sc, tile[nq * 4 + 1][dr] * sc,
                               tile[nq * 4 + 2][dr] * sc, tile[nq * 4 + 3][dr] * sc);
      *(unsigned int*)&gf8T[(size_t)(d0 + dr) * SEQ + n0 + nq * 4] = pk;
    }
  } else if (b < 6144) {
    // ---- tril-masked w -> fp8 (x 2^20) ----
    size_t e = (((size_t)(b - 2048)) * 256 + threadIdx.x) * 16;
    int m = (int)(e >> 12);    // row (4096 cols)
    int k = (int)(e & 4095);   // col (16-aligned)
    uint4 o;
    if (k > m) {               // fully above diagonal: zeros, no read
      o.x = o.y = o.z = o.w = 0u;
    } else {
      const float4* s4 = (const float4*)(w + e);
      float4 v0 = s4[0], v1 = s4[1], v2 = s4[2], v3 = s4[3];
      float vv[16] = {v0.x, v0.y, v0.z, v0.w, v1.x, v1.y, v1.z, v1.w,
                      v2.x, v2.y, v2.z, v2.w, v3.x, v3.y, v3.z, v3.w};
      if (k + 15 > m) {        // straddles diagonal: zero-mask above
#pragma unroll
        for (int j = 0; j < 16; j++) vv[j] = (k + j <= m) ? vv[j] : 0.0f;
      }
      o.x = pk4_f8(vv[0] * W_SCALE, vv[1] * W_SCALE, vv[2] * W_SCALE, vv[3] * W_SCALE);
      o.y = pk4_f8(vv[4] * W_SCALE, vv[5] * W_SCALE, vv[6] * W_SCALE, vv[7] * W_SCALE);
      o.z = pk4_f8(vv[8] * W_SCALE, vv[9] * W_SCALE, vv[10] * W_SCALE, vv[11] * W_SCALE);
      o.w = pk4_f8(vv[12] * W_SCALE, vv[13] * W_SCALE, vv[14] * W_SCALE, vv[15] * W_SCALE);
    }
    *(uint4*)(wf8 + e) = o;
  } else {
    // ---- proj_w transpose+cast -> projT[j][d] bf16 ----
    __shared__ float tile[64][65];
    int b2 = b - 6144;                 // [0,512)
    int j0 = (b2 & 15) * 64;           // out-col tile (0..1023)
    int d0 = (b2 >> 4) * 64;           // d tile (0..2047)
#pragma unroll
    for (int i = 0; i < 16; i++) {
      int idx = threadIdx.x + i * 256;
      int r = idx >> 6, c = idx & 63;  // r = d offset, c = j offset
      tile[r][c] = pw[(size_t)(d0 + r) * DOUT + j0 + c];
    }
    __syncthreads();
#pragma unroll
    for (int i = 0; i < 16; i++) {
      int idx = threadIdx.x + i * 256;
      int jr = idx >> 6, dc = idx & 63;
      pT[(size_t)(j0 + jr) * DH + d0 + dc] = f2bf(tile[dc][jr]);
    }
  }
}

// ---- GEMM1: fp8 MFMA, 64x64 tile, BK=128, counted-vmcnt 2-deep pipeline ---
// (unchanged from round 6: K-permuted b128 fragment reads -> 0 bank
// conflicts; XCD-chunked swizzle; PAIR causal {by0, 63-by0}, 33 uniform
// k-steps. Round-6 measured: 47us, MfmaUtil 27%.)

__global__ __launch_bounds__(256) void gemm_f8(const unsigned char* __restrict__ A,
                                               const unsigned char* __restrict__ BT,
                                               const float* __restrict__ xfull,
                                               const float* __restrict__ rbias,
                                               unsigned short* __restrict__ Pout) {
  constexpr int BK = 128;
  constexpr int ASZ = 64 * BK;   // 8 KB
  __shared__ unsigned char sA[2 * ASZ];
  __shared__ unsigned char sB[2 * ASZ];

  const int tid = threadIdx.x;
  const int lane = tid & 63, wave = tid >> 6;
  const int quad = lane >> 4, l16 = lane & 15;
  const int wm = wave >> 1, wn = wave & 1;
  const int K = SEQ;

  const int lin = blockIdx.x;
  const int sw = ((lin & 7) << 7) | (lin >> 3);  // chunked XCD swizzle
  const int bn0 = (sw >> 5) * 64;                // d-tile, confined per XCD
  const int by0 = sw & 31;                       // m-pair id

  for (int pass = 0; pass < 2; pass++) {
    const int by = pass == 0 ? by0 : 63 - by0;
    const int bm0 = by * 64;
    const int nt = (by + 2) >> 1;   // ceil(64*(by+1)/128); pair sums to 33

    const unsigned char* aP[2];
    const unsigned char* bP[2];
#pragma unroll
    for (int r = 0; r < 2; r++) {
      int idx = r * 256 + tid;
      int row = idx >> 3;
      int col = ((idx & 7) ^ (row & 7)) * 16;
      aP[r] = A + (size_t)(bm0 + row) * K + col;
      bP[r] = BT + (size_t)(bn0 + row) * K + col;
    }

    f32x4 acc[2][2] = {};

    auto stage = [&](int buf) {
#pragma unroll
      for (int r = 0; r < 2; r++) {
        g2l16(aP[r], &sA[buf * ASZ + (r * 256 + tid) * 16]);
        aP[r] += BK;
      }
#pragma unroll
      for (int r = 0; r < 2; r++) {
        g2l16(bP[r], &sB[buf * ASZ + (r * 256 + tid) * 16]);
        bP[r] += BK;
      }
    };

    auto compute = [&](int buf) {
      const unsigned char* bA = &sA[buf * ASZ];
      const unsigned char* bB = &sB[buf * ASZ];
      long a8[4][2], b8[4][2];
#pragma unroll
      for (int i = 0; i < 2; i++) {
        int R = wm * 32 + i * 16 + l16;
        const unsigned char* rowp = &bA[R * BK];
        int s = R & 7;
        longx2 X = *(const longx2*)&rowp[(quad ^ s) * 16];
        longx2 Y = *(const longx2*)&rowp[((quad + 4) ^ s) * 16];
        a8[0][i] = X[0]; a8[1][i] = X[1]; a8[2][i] = Y[0]; a8[3][i] = Y[1];
      }
#pragma unroll
      for (int j = 0; j < 2; j++) {
        int R = wn * 32 + j * 16 + l16;
        const unsigned char* rowp = &bB[R * BK];
        int s = R & 7;
        longx2 X = *(const longx2*)&rowp[(quad ^ s) * 16];
        longx2 Y = *(const longx2*)&rowp[((quad + 4) ^ s) * 16];
        b8[0][j] = X[0]; b8[1][j] = X[1]; b8[2][j] = Y[0]; b8[3][j] = Y[1];
      }
#pragma unroll
      for (int h = 0; h < 4; h++)
#pragma unroll
        for (int i = 0; i < 2; i++)
#pragma unroll
          for (int j = 0; j < 2; j++)
            acc[i][j] = __builtin_amdgcn_mfma_f32_16x16x32_fp8_fp8(a8[h][i], b8[h][j], acc[i][j], 0, 0, 0);
    };

    stage(0);
    int cur = 0;
    for (int t = 0; t < nt; t++) {
      if (t + 1 < nt) {
        stage(cur ^ 1);
        asm volatile("s_waitcnt vmcnt(4)" ::: "memory");
      } else {
        asm volatile("s_waitcnt vmcnt(0)" ::: "memory");
      }
      __builtin_amdgcn_s_barrier();   // buf `cur` fully staged
      compute(cur);
      __builtin_amdgcn_s_barrier();   // all waves done reading buf `cur`
      cur ^= 1;
    }

    // epilogue — C/D layout: col = lane&15, row = quad*4 + reg (m89-verified)
#pragma unroll
    for (int i = 0; i < 2; i++) {
#pragma unroll
      for (int j = 0; j < 2; j++) {
        int col = bn0 + wn * 32 + j * 16 + l16;
#pragma unroll
        for (int r = 0; r < 4; r++) {
          int row = bm0 + wm * 32 + i * 16 + quad * 4 + r;
          float g = acc[i][j][r] * W_SCALE_INV + rbias[row];
          float pv = xfull[(size_t)row * (2 * DH) + col] * g;
          Pout[(size_t)row * DH + col] = f2bf(pv);
        }
      }
    }
  }
}

// ---- GEMM2: bf16 MFMA, 64x64 tile, BK=64, counted-vmcnt (unchanged) -------

__global__ __launch_bounds__(256) void gemm_bf(const unsigned short* __restrict__ A,
                                               const unsigned short* __restrict__ BT,
                                               const float* __restrict__ cbias,
                                               float* __restrict__ out,
                                               int N, int K) {
  constexpr int BK = 64;
  constexpr int ASZ = 64 * BK;   // elems (8 KB)
  __shared__ unsigned short sA[2 * ASZ];
  __shared__ unsigned short sB[2 * ASZ];

  const int tid = threadIdx.x;
  const int lane = tid & 63, wave = tid >> 6;
  const int quad = lane >> 4, l16 = lane & 15;
  const int wm = wave >> 1, wn = wave & 1;

  const int lin = blockIdx.x;
  const int sw = ((lin & 7) << 7) | (lin >> 3);  // chunked XCD swizzle
  const int bn0 = (sw & 15) * 64;
  const int bm0 = (sw >> 4) * 64;                // m-tile, confined per XCD
  const int nt = K / BK;

  const unsigned short* aP[2];
  const unsigned short* bP[2];
#pragma unroll
  for (int r = 0; r < 2; r++) {
    int idx = r * 256 + tid;
    int row = idx >> 3;
    int col = ((idx & 7) ^ (row & 7)) * 8;
    aP[r] = A + (size_t)(bm0 + row) * K + col;
    bP[r] = BT + (size_t)(bn0 + row) * K + col;
  }

  f32x4 acc[2][2] = {};

  auto stage = [&](int buf) {
#pragma unroll
    for (int r = 0; r < 2; r++) {
      g2l16(aP[r], &sA[buf * ASZ + (r * 256 + tid) * 8]);
      aP[r] += BK;
    }
#pragma unroll
    for (int r = 0; r < 2; r++) {
      g2l16(bP[r], &sB[buf * ASZ + (r * 256 + tid) * 8]);
      bP[r] += BK;
    }
  };

  auto compute = [&](int buf) {
    const unsigned short* bA = &sA[buf * ASZ];
    const unsigned short* bB = &sB[buf * ASZ];
    bf16x8 af[2][2], bfr[2][2];
#pragma unroll
    for (int h = 0; h < 2; h++) {
#pragma unroll
      for (int i = 0; i < 2; i++) {
        int R = wm * 32 + i * 16 + l16;
        af[h][i] = *(const bf16x8*)&bA[R * BK + (((h * 4 + quad) ^ (R & 7)) * 8)];
      }
#pragma unroll
      for (int j = 0; j < 2; j++) {
        int R = wn * 32 + j * 16 + l16;
        bfr[h][j] = *(const bf16x8*)&bB[R * BK + (((h * 4 + quad) ^ (R & 7)) * 8)];
      }
    }
#pragma unroll
    for (int h = 0; h < 2; h++)
#pragma unroll
      for (int i = 0; i < 2; i++)
#pragma unroll
        for (int j = 0; j < 2; j++)
          acc[i][j] = __builtin_amdgcn_mfma_f32_16x16x32_bf16(af[h][i], bfr[h][j], acc[i][j], 0, 0, 0);
  };

  stage(0);
  int cur = 0;
  for (int t = 0; t < nt; t++) {
    if (t + 1 < nt) {
      stage(cur ^ 1);
      asm volatile("s_waitcnt vmcnt(4)" ::: "memory");
    } else {
      asm volatile("s_waitcnt vmcnt(0)" ::: "memory");
    }
    __builtin_amdgcn_s_barrier();
    compute(cur);
    __builtin_amdgcn_s_barrier();
    cur ^= 1;
  }

#pragma unroll
  for (int i = 0; i < 2; i++) {
#pragma unroll
    for (int j = 0; j < 2; j++) {
      int col = bn0 + wn * 32 + j * 16 + l16;
#pragma unroll
      for (int r = 0; r < 4; r++) {
        int row = bm0 + wm * 32 + i * 16 + quad * 4 + r;
        out[(size_t)row * N + col] = acc[i][j][r] + cbias[col];
      }
    }
  }
}

// ---- launch ---------------------------------------------------------------

extern "C" void kernel_launch(void* const* d_in, const int* in_sizes, int n_in,
                              void* d_out, int out_size, void* d_ws, size_t ws_size,
                              hipStream_t stream) {
  (void)in_sizes; (void)n_in; (void)out_size; (void)ws_size;
  const float* x   = (const float*)d_in[0];
  const float* lns = (const float*)d_in[1];
  const float* w   = (const float*)d_in[2];
  const float* sb  = (const float*)d_in[3];
  const float* pw  = (const float*)d_in[4];
  const float* pb  = (const float*)d_in[5];
  float* out = (float*)d_out;

  char* p = (char*)d_ws;
  unsigned char*  wf8   = (unsigned char*)p;  p += (size_t)SEQ * SEQ;        // 16 MB
  unsigned char*  gf8T  = (unsigned char*)p;  p += (size_t)DH * SEQ;         //  8 MB
  unsigned short* projT = (unsigned short*)p; p += (size_t)DOUT * DH * 2;    //  4 MB
  unsigned short* Pbuf  = (unsigned short*)p; p += (size_t)SEQ * DH * 2;     // 16 MB
  float* mv = (float*)p; p += (size_t)SEQ * 4;
  float* rv = (float*)p; p += (size_t)SEQ * 4;

  // prep: stats first (gates norm), then one fused kernel for everything else
  ln_stats<<<SEQ, 256, 0, stream>>>(x, mv, rv);
  prep2<<<2048 + 4096 + 512, 256, 0, stream>>>(x, mv, rv, lns, gf8T, w, wf8, pw, projT);

  // GEMM1 (fp8): gate2 = tril(w) @ gate  (M=4096, N=2048, K=4096, causal)
  gemm_f8<<<1024, 256, 0, stream>>>(wf8, gf8T, x, sb, Pbuf);

  // GEMM2 (bf16): out = P @ proj_w + proj_b  (M=4096, N=1024, K=2048)
  gemm_bf<<<1024, 256, 0, stream>>>(Pbuf, projT, pb, out, DOUT, DH);
}